// Round 1
// baseline (95.892 us; speedup 1.0000x reference)
//
#include <hip/hip_runtime.h>
#include <limits.h>

// Input: features [32, 512, 64, 64] f32 (contiguous, w innermost).
// Output: 14 f32 scalars = SPP maxes for k=1,2,3.
//
// Strategy: memory-bound single pass.
//  - Stage A: init per-position scratch P[4096] (one int per (h,w)) to INT_MIN.
//  - Stage B: reduce over the 16384 (b,c) images; each thread owns 4 fixed
//    spatial positions (one float4) -> static-indexed register accumulators,
//    coalesced loads; finish with 4 global atomicMax using an order-preserving
//    float->int key.
//  - Stage C: 14 blocks fold P[4096] into the 14 bins and write d_out.

#define NIMG 16384          // 32*512 images
#define IMG_F4 1024         // 64*64/4 float4s per image
#define IMGS_PER_BLOCK 32
#define MAIN_BLOCKS (NIMG / IMGS_PER_BLOCK)   // 512

// Order-preserving float<->int key (involution). Valid for non-NaN.
__device__ __forceinline__ int fkey(float f) {
    int i = __float_as_int(f);
    return i >= 0 ? i : i ^ 0x7fffffff;
}

__global__ void spp_init(int* __restrict__ P) {
    int i = blockIdx.x * blockDim.x + threadIdx.x;
    if (i < 4096) P[i] = INT_MIN;
}

__global__ __launch_bounds__(1024, 8)
void spp_main(const float4* __restrict__ in, int* __restrict__ P) {
    const int t = threadIdx.x;   // 0..1023: owns spatial positions 4t..4t+3
    const long long base = (long long)blockIdx.x * IMGS_PER_BLOCK * IMG_F4 + t;

    float4 m = in[base];
    #pragma unroll 4
    for (int img = 1; img < IMGS_PER_BLOCK; ++img) {
        float4 v = in[base + (long long)img * IMG_F4];
        m.x = fmaxf(m.x, v.x);
        m.y = fmaxf(m.y, v.y);
        m.z = fmaxf(m.z, v.z);
        m.w = fmaxf(m.w, v.w);
    }

    const int p = t * 4;
    atomicMax(&P[p + 0], fkey(m.x));
    atomicMax(&P[p + 1], fkey(m.y));
    atomicMax(&P[p + 2], fkey(m.z));
    atomicMax(&P[p + 3], fkey(m.w));
}

__global__ void spp_final(const int* __restrict__ P, float* __restrict__ out) {
    const int bin = blockIdx.x;  // 0..13
    const int t = threadIdx.x;   // 256 threads

    int best = INT_MIN;
    for (int p = t; p < 4096; p += 256) {
        const int h = p >> 6, w = p & 63;
        bool in_bin;
        if (bin == 0) {
            in_bin = true;                                    // k=1
        } else if (bin < 5) {
            in_bin = (((h >> 5) << 1) | (w >> 5)) == (bin - 1);   // k=2
        } else {
            in_bin = (h < 63) && (w < 63) &&
                     ((h / 21) * 3 + (w / 21)) == (bin - 5);      // k=3
        }
        if (in_bin) best = max(best, P[p]);
    }

    // wave (64-lane) shuffle reduce, then cross-wave via LDS
    #pragma unroll
    for (int off = 32; off > 0; off >>= 1)
        best = max(best, __shfl_down(best, off, 64));

    __shared__ int sm[4];
    if ((t & 63) == 0) sm[t >> 6] = best;
    __syncthreads();
    if (t == 0) {
        int r = max(max(sm[0], sm[1]), max(sm[2], sm[3]));
        out[bin] = __int_as_float(r >= 0 ? r : r ^ 0x7fffffff);
    }
}

extern "C" void kernel_launch(void* const* d_in, const int* in_sizes, int n_in,
                              void* d_out, int out_size, void* d_ws, size_t ws_size,
                              hipStream_t stream) {
    const float4* in = (const float4*)d_in[0];
    float* out = (float*)d_out;
    int* P = (int*)d_ws;   // 4096 ints = 16 KiB scratch

    spp_init<<<16, 256, 0, stream>>>(P);
    spp_main<<<MAIN_BLOCKS, 1024, 0, stream>>>(in, P);
    spp_final<<<14, 256, 0, stream>>>(P, out);
}

// Round 2
// 57.494 us; speedup vs baseline: 1.6679x; 1.6679x over previous
//
#include <hip/hip_runtime.h>
#include <math.h>

// Input: features [32, 512, 64, 64] f32. Output: 14 f32 SPP maxes (k=1,2,3).
//
// spp_main: 512 blocks x 1024 threads. Block b reduces images [32b, 32b+32)
// (a contiguous 2 MiB region) over the image axis into 4096 per-position
// maxes (thread t owns positions 4t..4t+3, one float4 -> static register
// accumulators, coalesced 16B/lane loads). Positions staged in LDS
// (sm[p], p = h*64 + w), then wave q (q<14) reduces bin q: bin membership is
// a row range (h = LDS row index) x a per-lane w-mask (w = lane id).
// One plain float store per (block, bin) -> P2[512][14]. No atomics, no init.
//
// spp_final: 1 block; wave q folds P2[:, q] (512 values) -> d_out[q].

#define IMG_F4 1024          // 64*64/4 float4s per image (16 KiB)
#define IMGS_PER_BLOCK 32
#define MAIN_BLOCKS 512      // 16384 images / 32
#define NBIN 14

__device__ __forceinline__ void fmax4(float4& m, const float4 v) {
    m.x = fmaxf(m.x, v.x);
    m.y = fmaxf(m.y, v.y);
    m.z = fmaxf(m.z, v.z);
    m.w = fmaxf(m.w, v.w);
}

__global__ __launch_bounds__(1024, 8)
void spp_main(const float4* __restrict__ in, float* __restrict__ P2) {
    const int t = threadIdx.x;
    const long long base = (long long)blockIdx.x * (IMGS_PER_BLOCK * IMG_F4) + t;

    // image-axis reduction: two accumulators break the fmax dependence chain
    float4 m0 = in[base];
    float4 m1 = in[base + IMG_F4];
    #pragma unroll 5
    for (int img = 2; img < IMGS_PER_BLOCK; img += 2) {
        float4 a = in[base + (long long)img * IMG_F4];
        float4 b = in[base + (long long)(img + 1) * IMG_F4];
        fmax4(m0, a);
        fmax4(m1, b);
    }
    fmax4(m0, m1);

    // stage per-position maxes: sm[4t + e], i.e. sm[h*64 + w]
    __shared__ float sm[4096];
    *(float4*)&sm[t * 4] = m0;
    __syncthreads();

    const int q = t >> 6;     // wave id = bin id
    const int l = t & 63;     // lane id = w coordinate
    if (q < NBIN) {
        int rstart, rcount;
        bool wmask;
        if (q == 0) {                       // k=1: whole map
            rstart = 0; rcount = 64; wmask = true;
        } else if (q < 5) {                 // k=2: 32x32 blocks
            const int b = q - 1;
            rstart = (b >> 1) * 32; rcount = 32;
            wmask = ((l >> 5) == (b & 1));
        } else {                            // k=3: 21x21 blocks, row/col 63 excluded
            const int b = q - 5;
            rstart = (b / 3) * 21; rcount = 21;
            wmask = (l < 63) && ((l / 21) == (b % 3));
        }

        float best = -INFINITY;
        for (int i = 0; i < rcount; ++i)
            best = fmaxf(best, sm[(rstart + i) * 64 + l]);
        if (!wmask) best = -INFINITY;

        #pragma unroll
        for (int off = 32; off > 0; off >>= 1)
            best = fmaxf(best, __shfl_down(best, off, 64));

        if (l == 0) P2[blockIdx.x * NBIN + q] = best;
    }
}

__global__ __launch_bounds__(1024)
void spp_final(const float* __restrict__ P2, float* __restrict__ out) {
    const int q = threadIdx.x >> 6;
    const int l = threadIdx.x & 63;
    if (q >= NBIN) return;

    float best = -INFINITY;
    for (int j = l; j < MAIN_BLOCKS; j += 64)
        best = fmaxf(best, P2[j * NBIN + q]);

    #pragma unroll
    for (int off = 32; off > 0; off >>= 1)
        best = fmaxf(best, __shfl_down(best, off, 64));

    if (l == 0) out[q] = best;
}

extern "C" void kernel_launch(void* const* d_in, const int* in_sizes, int n_in,
                              void* d_out, int out_size, void* d_ws, size_t ws_size,
                              hipStream_t stream) {
    const float4* in = (const float4*)d_in[0];
    float* out = (float*)d_out;
    float* P2 = (float*)d_ws;   // 512*14 floats = 28 KiB scratch

    spp_main<<<MAIN_BLOCKS, 1024, 0, stream>>>(in, P2);
    spp_final<<<1, 1024, 0, stream>>>(P2, out);
}